// Round 14
// baseline (63.477 us; speedup 1.0000x reference)
//
#include <hip/hip_runtime.h>

#define NTHREADS 256
#define EPT      8              // elements per thread per chunk
#define CHUNK    (NTHREADS*EPT) // 2048 elements
#define ROWS     16
#define NB       2048           // 8 blocks/CU on 256 CUs
#define BPR      (NB/ROWS)      // 128 blocks per row
#define CPB      4              // chunks per block

#define C_TREND   0.6f
#define C_DETAIL  0.85f
#define C_SPIKE_T 3.5f
#define C_SPIKE_D 0.35f
#define C_EPS     1e-6f

// LDS skew: lane-stride 8 floats -> 9 words after skew (9 coprime 32 banks)
#define SKEW(m) ((m) + ((m) >> 3))

typedef float vfloat4 __attribute__((ext_vector_type(4)));

__device__ __forceinline__ float reflect_load(const float* __restrict__ rp, int g, int L) {
    if (g < 0) g = -g;
    else if (g >= L) g = 2 * L - 2 - g;
    return rp[g];
}

// Deterministic block reduce of (s,s2).
__device__ __forceinline__ void blk_reduce2(double& s, double& s2) {
    #pragma unroll
    for (int off = 32; off > 0; off >>= 1) {
        s  += __shfl_xor(s, off);
        s2 += __shfl_xor(s2, off);
    }
    __shared__ double lds[8];
    int wid = threadIdx.x >> 6, lane = threadIdx.x & 63;
    if (lane == 0) { lds[2*wid] = s; lds[2*wid+1] = s2; }
    __syncthreads();
    s  = lds[0] + lds[2] + lds[4] + lds[6];
    s2 = lds[1] + lds[3] + lds[5] + lds[7];
}

__device__ __forceinline__ float var_to_thr(double s, double s2, int L) {
    double n = (double)L;
    double var = (s2 - s * s / n) / (n - 1.0);
    float stdv = (float)sqrt(fmax(var, 0.0));
    return fmaxf(stdv, C_EPS) * C_SPIKE_T;
}

// thr from 128 (s,s2) pairs; identical value in every block (fixed order).
__device__ __forceinline__ float thr128(const double* __restrict__ prow, int L) {
    __shared__ float thr_s;
    if (threadIdx.x < 64) {
        int l = threadIdx.x;
        double s  = prow[2*l + 0] + prow[2*(l+64) + 0];
        double s2 = prow[2*l + 1] + prow[2*(l+64) + 1];
        #pragma unroll
        for (int off = 32; off > 0; off >>= 1) {
            s  += __shfl_xor(s, off);
            s2 += __shfl_xor(s2, off);
        }
        if (threadIdx.x == 0) thr_s = var_to_thr(s, s2, L);
    }
    __syncthreads();
    return thr_s;
}

// scalar pass-1 output at logical position p (global reflect loads; L1-hot)
__device__ float xp1_scalar(const float* __restrict__ rp, int L, int p, float thr) {
    if (p < 0) p = -p;
    else if (p >= L) p = 2 * L - 2 - p;
    float s5 = 0.f, s11 = 0.f;
    #pragma unroll
    for (int k = -5; k <= 5; ++k) {
        float v = reflect_load(rp, p + k, L);
        s11 += v;
        if (k >= -2 && k <= 2) s5 += v;
    }
    float local = s5 * 0.2f;
    float trend = s11 * (1.0f / 11.0f);
    float r = rp[p] - local;
    r = (fabsf(r) > thr) ? r * C_SPIKE_D : r;
    return (1.0f - C_TREND) * local + C_TREND * trend + C_DETAIL * r;
}

// load w[24] = x[o-8 .. o+15] (vectorized when interior)
__device__ __forceinline__ void load_w24(const float* __restrict__ rp, int o, int L, float w[24]) {
    if (o >= 8 && o + 16 <= L) {
        const float4* p = reinterpret_cast<const float4*>(rp + o - 8);
        #pragma unroll
        for (int j = 0; j < 6; ++j) {
            float4 v = p[j];
            w[4*j+0] = v.x; w[4*j+1] = v.y; w[4*j+2] = v.z; w[4*j+3] = v.w;
        }
    } else {
        #pragma unroll
        for (int j = 0; j < 24; ++j) w[j] = reflect_load(rp, o - 8 + j, L);
    }
}

// pv[k] = xp1 at o+k (k=0..7) from w[24] (w[j] = x[o-8+j]).
// TWO independent 4-step chains (A: k=0..3, B: k=4..7) for ILP.
__device__ __forceinline__ void xp1_slide8(const float w[24], float t1, float pv[8]) {
    float s5a  = w[6]+w[7]+w[8]+w[9]+w[10];                         // x[o-2..o+2]
    float s11a = w[3]+w[4]+w[5]+w[6]+w[7]+w[8]+w[9]+w[10]+w[11]+w[12]+w[13];
    float s5b  = w[10]+w[11]+w[12]+w[13]+w[14];                     // x[o+2..o+6]
    float s11b = w[7]+w[8]+w[9]+w[10]+w[11]+w[12]+w[13]+w[14]+w[15]+w[16]+w[17];
    #pragma unroll
    for (int k = 0; k < 4; ++k) {
        {
            float local = s5a * 0.2f;
            float trend = s11a * (1.0f / 11.0f);
            float r = w[8 + k] - local;
            r = (fabsf(r) > t1) ? r * C_SPIKE_D : r;
            pv[k] = (1.0f - C_TREND) * local + C_TREND * trend + C_DETAIL * r;
            if (k < 3) { s5a += w[11+k] - w[6+k]; s11a += w[14+k] - w[3+k]; }
        }
        {
            float local = s5b * 0.2f;
            float trend = s11b * (1.0f / 11.0f);
            float r = w[12 + k] - local;
            r = (fabsf(r) > t1) ? r * C_SPIKE_D : r;
            pv[4 + k] = (1.0f - C_TREND) * local + C_TREND * trend + C_DETAIL * r;
            if (k < 3) { s5b += w[15+k] - w[10+k]; s11b += w[18+k] - w[7+k]; }
        }
    }
}

// ---- K1: pass-1 residual partials (two independent chains) ----
__global__ __launch_bounds__(NTHREADS) void k1_reduce(
    const float* __restrict__ x, double* __restrict__ partials1, int L) {
    int row = blockIdx.x / BPR, cgid = blockIdx.x % BPR;
    const float* rp = x + (size_t)row * L;
    double s = 0.0, s2 = 0.0;
    for (int i = 0; i < CPB; ++i) {
        int o = (cgid * CPB + i) * CHUNK + threadIdx.x * EPT;
        float w[16];   // x[o-4 .. o+11]
        if (o >= 4 && o + 12 <= L) {
            const float4* p = reinterpret_cast<const float4*>(rp + o - 4);
            #pragma unroll
            for (int j = 0; j < 4; ++j) {
                float4 v = p[j];
                w[4*j+0] = v.x; w[4*j+1] = v.y; w[4*j+2] = v.z; w[4*j+3] = v.w;
            }
        } else {
            #pragma unroll
            for (int j = 0; j < 16; ++j) w[j] = reflect_load(rp, o - 4 + j, L);
        }
        float s5a = w[2]+w[3]+w[4]+w[5]+w[6];     // x[o-2..o+2]
        float s5b = w[6]+w[7]+w[8]+w[9]+w[10];    // x[o+2..o+6]
        #pragma unroll
        for (int k = 0; k < 4; ++k) {
            {
                float r = w[4 + k] - s5a * 0.2f;
                s += (double)r;
                s2 = fma((double)r, (double)r, s2);
                if (k < 3) s5a += w[7+k] - w[2+k];
            }
            {
                float r = w[8 + k] - s5b * 0.2f;
                s += (double)r;
                s2 = fma((double)r, (double)r, s2);
                if (k < 3) s5b += w[11+k] - w[6+k];
            }
        }
    }
    blk_reduce2(s, s2);
    if (threadIdx.x == 0) { partials1[2*blockIdx.x] = s; partials1[2*blockIdx.x+1] = s2; }
}

// ---- K2: direct-global x window; xp1 own-8 -> LDS (halo +-2); pass-2 partials ----
__global__ __launch_bounds__(NTHREADS) void k2_reduce(
    const float* __restrict__ x, const double* __restrict__ partials1,
    double* __restrict__ partials2, int L) {
    __shared__ float xp[SKEW(CHUNK + 4 - 1) + 1];    // m2 in [0, CHUNK+3]
    int row = blockIdx.x / BPR, cgid = blockIdx.x % BPR;
    const float* rp = x + (size_t)row * L;
    float t1 = thr128(partials1 + (size_t)row * 2 * BPR, L);
    int tid = threadIdx.x;
    double s = 0.0, s2 = 0.0;
    for (int i = 0; i < CPB; ++i) {
        int cb = (cgid * CPB + i) * CHUNK;
        int o = cb + tid * EPT;
        float w[24];
        load_w24(rp, o, L, w);
        float pv[8];
        xp1_slide8(w, t1, pv);
        int m2b = tid * EPT + 2;
        #pragma unroll
        for (int k = 0; k < 8; ++k) xp[SKEW(m2b + k)] = pv[k];
        if (tid < 2)                     xp[SKEW(tid)] = xp1_scalar(rp, L, cb - 2 + tid, t1);
        else if (tid >= 64 && tid < 66)  xp[SKEW(CHUNK + 2 + (tid-64))] = xp1_scalar(rp, L, cb + CHUNK + (tid-64), t1);
        __syncthreads();
        float v2[12];   // xp1 at [o-2 .. o+9]
        v2[0] = xp[SKEW(m2b - 2)];
        v2[1] = xp[SKEW(m2b - 1)];
        #pragma unroll
        for (int k = 0; k < 8; ++k) v2[2+k] = pv[k];
        v2[10] = xp[SKEW(m2b + 8)];
        v2[11] = xp[SKEW(m2b + 9)];
        float t5a = v2[0]+v2[1]+v2[2]+v2[3]+v2[4];
        float t5b = v2[4]+v2[5]+v2[6]+v2[7]+v2[8];
        #pragma unroll
        for (int k = 0; k < 4; ++k) {
            {
                float r2 = v2[2+k] - t5a * 0.2f;
                s += (double)r2;
                s2 = fma((double)r2, (double)r2, s2);
                if (k < 3) t5a += v2[5+k] - v2[k];
            }
            {
                float r2 = v2[6+k] - t5b * 0.2f;
                s += (double)r2;
                s2 = fma((double)r2, (double)r2, s2);
                if (k < 3) t5b += v2[9+k] - v2[4+k];
            }
        }
        __syncthreads();   // protect xp reuse next chunk
    }
    blk_reduce2(s, s2);
    if (threadIdx.x == 0) { partials2[2*blockIdx.x] = s; partials2[2*blockIdx.x+1] = s2; }
}

// ---- K3: direct-global x window; xp1 own-8 -> LDS (halo +-5); apply; write out ----
__global__ __launch_bounds__(NTHREADS) void k3_apply(
    const float* __restrict__ x, const double* __restrict__ partials1,
    const double* __restrict__ partials2, float* __restrict__ out, int L) {
    __shared__ float xp[SKEW(CHUNK + 10 - 1) + 1];   // m2 in [0, CHUNK+9]
    int row = blockIdx.x / BPR, cgid = blockIdx.x % BPR;
    const float* rp = x + (size_t)row * L;
    float* orow = out + (size_t)row * L;
    float t1 = thr128(partials1 + (size_t)row * 2 * BPR, L);
    float t2 = thr128(partials2 + (size_t)row * 2 * BPR, L);
    int tid = threadIdx.x;
    for (int i = 0; i < CPB; ++i) {
        int cb = (cgid * CPB + i) * CHUNK;
        int o = cb + tid * EPT;
        float w[24];
        load_w24(rp, o, L, w);
        float pv[8];
        xp1_slide8(w, t1, pv);
        int m2b = tid * EPT + 5;
        #pragma unroll
        for (int k = 0; k < 8; ++k) xp[SKEW(m2b + k)] = pv[k];
        if (tid < 5)                     xp[SKEW(tid)] = xp1_scalar(rp, L, cb - 5 + tid, t1);
        else if (tid >= 64 && tid < 69)  xp[SKEW(CHUNK + 5 + (tid-64))] = xp1_scalar(rp, L, cb + CHUNK + (tid-64), t1);
        __syncthreads();
        float w2[18];   // xp1 at [o-5 .. o+12]
        #pragma unroll
        for (int j = 0; j < 5; ++j) w2[j]    = xp[SKEW(m2b - 5 + j)];
        #pragma unroll
        for (int k = 0; k < 8; ++k) w2[5+k]  = pv[k];
        #pragma unroll
        for (int j = 0; j < 5; ++j) w2[13+j] = xp[SKEW(m2b + 8 + j)];
        float res[EPT];
        {
            float s5a  = w2[3]+w2[4]+w2[5]+w2[6]+w2[7];       // xp1[o-2..o+2]
            float s11a = w2[0]+w2[1]+w2[2]+w2[3]+w2[4]+w2[5]
                       + w2[6]+w2[7]+w2[8]+w2[9]+w2[10];
            float s5b  = w2[7]+w2[8]+w2[9]+w2[10]+w2[11];     // xp1[o+2..o+6]
            float s11b = w2[4]+w2[5]+w2[6]+w2[7]+w2[8]+w2[9]
                       + w2[10]+w2[11]+w2[12]+w2[13]+w2[14];
            #pragma unroll
            for (int k = 0; k < 4; ++k) {
                {
                    float local = s5a * 0.2f;
                    float trend = s11a * (1.0f / 11.0f);
                    float r = w2[5+k] - local;
                    r = (fabsf(r) > t2) ? r * C_SPIKE_D : r;
                    res[k] = (1.0f - C_TREND) * local + C_TREND * trend + C_DETAIL * r;
                    if (k < 3) { s5a += w2[8+k] - w2[3+k]; s11a += w2[11+k] - w2[k]; }
                }
                {
                    float local = s5b * 0.2f;
                    float trend = s11b * (1.0f / 11.0f);
                    float r = w2[9+k] - local;
                    r = (fabsf(r) > t2) ? r * C_SPIKE_D : r;
                    res[4+k] = (1.0f - C_TREND) * local + C_TREND * trend + C_DETAIL * r;
                    if (k < 3) { s5b += w2[12+k] - w2[7+k]; s11b += w2[15+k] - w2[4+k]; }
                }
            }
        }
        vfloat4 r0 = { res[0], res[1], res[2], res[3] };
        vfloat4 r1 = { res[4], res[5], res[6], res[7] };
        __builtin_nontemporal_store(r0, reinterpret_cast<vfloat4*>(orow + o));
        __builtin_nontemporal_store(r1, reinterpret_cast<vfloat4*>(orow + o) + 1);
        __syncthreads();   // protect xp reuse next chunk
    }
}

extern "C" void kernel_launch(void* const* d_in, const int* in_sizes, int n_in,
                              void* d_out, int out_size, void* d_ws, size_t ws_size,
                              hipStream_t stream) {
    const float* x = (const float*)d_in[0];
    float* outp = (float*)d_out;

    int total = in_sizes[0];
    int L = total / ROWS;          // 1048576

    // workspace: [partials1 32KB][partials2 32KB]
    double* partials1 = (double*)d_ws;
    double* partials2 = partials1 + 2 * NB;

    k1_reduce<<<NB, NTHREADS, 0, stream>>>(x, partials1, L);
    k2_reduce<<<NB, NTHREADS, 0, stream>>>(x, partials1, partials2, L);
    k3_apply <<<NB, NTHREADS, 0, stream>>>(x, partials1, partials2, outp, L);
}

// Round 15
// 57.547 us; speedup vs baseline: 1.1030x; 1.1030x over previous
//
#include <hip/hip_runtime.h>

#define NTHREADS 256
#define EPT      8              // elements per thread per chunk
#define CHUNK    (NTHREADS*EPT) // 2048 elements
#define ROWS     16
#define NB       2048           // 8 blocks/CU on 256 CUs
#define BPR      (NB/ROWS)      // 128 blocks per row
#define CPB      4              // chunks per block

#define C_TREND   0.6f
#define C_DETAIL  0.85f
#define C_SPIKE_T 3.5f
#define C_SPIKE_D 0.35f
#define C_EPS     1e-6f
// blend folded: out = 0.85*r_d + (0.08*s5 + (0.6/11)*s11)
#define B5   0.08f
#define B11  0.05454545454545454f

// LDS skew: lane-stride 8 floats -> 9 words after skew (9 coprime 32 banks)
#define SKEW(m) ((m) + ((m) >> 3))

typedef float vfloat4 __attribute__((ext_vector_type(4)));

__device__ __forceinline__ float reflect_load(const float* __restrict__ rp, int g, int L) {
    if (g < 0) g = -g;
    else if (g >= L) g = 2 * L - 2 - g;
    return rp[g];
}

// Deterministic block reduce of (s,s2).
__device__ __forceinline__ void blk_reduce2(double& s, double& s2) {
    #pragma unroll
    for (int off = 32; off > 0; off >>= 1) {
        s  += __shfl_xor(s, off);
        s2 += __shfl_xor(s2, off);
    }
    __shared__ double lds[8];
    int wid = threadIdx.x >> 6, lane = threadIdx.x & 63;
    if (lane == 0) { lds[2*wid] = s; lds[2*wid+1] = s2; }
    __syncthreads();
    s  = lds[0] + lds[2] + lds[4] + lds[6];
    s2 = lds[1] + lds[3] + lds[5] + lds[7];
}

__device__ __forceinline__ float var_to_thr(double s, double s2, int L) {
    double n = (double)L;
    double var = (s2 - s * s / n) / (n - 1.0);
    float stdv = (float)sqrt(fmax(var, 0.0));
    return fmaxf(stdv, C_EPS) * C_SPIKE_T;
}

// thr from 128 (s,s2) pairs; identical value in every block (fixed order).
__device__ __forceinline__ float thr128(const double* __restrict__ prow, int L) {
    __shared__ float thr_s;
    if (threadIdx.x < 64) {
        int l = threadIdx.x;
        double s  = prow[2*l + 0] + prow[2*(l+64) + 0];
        double s2 = prow[2*l + 1] + prow[2*(l+64) + 1];
        #pragma unroll
        for (int off = 32; off > 0; off >>= 1) {
            s  += __shfl_xor(s, off);
            s2 += __shfl_xor(s2, off);
        }
        if (threadIdx.x == 0) thr_s = var_to_thr(s, s2, L);
    }
    __syncthreads();
    return thr_s;
}

// scalar pass-1 output at logical position p (global reflect loads; L1-hot)
__device__ float xp1_scalar(const float* __restrict__ rp, int L, int p, float thr) {
    if (p < 0) p = -p;
    else if (p >= L) p = 2 * L - 2 - p;
    float s5 = 0.f, s11 = 0.f;
    #pragma unroll
    for (int k = -5; k <= 5; ++k) {
        float v = reflect_load(rp, p + k, L);
        s11 += v;
        if (k >= -2 && k <= 2) s5 += v;
    }
    float r = fmaf(-0.2f, s5, rp[p]);
    r = (fabsf(r) > thr) ? r * C_SPIKE_D : r;
    return fmaf(C_DETAIL, r, fmaf(B11, s11, B5 * s5));
}

// load w[24] = x[o-8 .. o+15] (vectorized when interior)
__device__ __forceinline__ void load_w24(const float* __restrict__ rp, int o, int L, float w[24]) {
    if (o >= 8 && o + 16 <= L) {
        const float4* p = reinterpret_cast<const float4*>(rp + o - 8);
        #pragma unroll
        for (int j = 0; j < 6; ++j) {
            float4 v = p[j];
            w[4*j+0] = v.x; w[4*j+1] = v.y; w[4*j+2] = v.z; w[4*j+3] = v.w;
        }
    } else {
        #pragma unroll
        for (int j = 0; j < 24; ++j) w[j] = reflect_load(rp, o - 8 + j, L);
    }
}

// pv[k] = xp1 at o+k (k=0..7) from w[24] (w[j] = x[o-8+j]). Single chain, FMA blend.
__device__ __forceinline__ void xp1_slide8(const float w[24], float t1, float pv[8]) {
    float s5  = w[6] + w[7] + w[8] + w[9] + w[10];                 // x[o-2..o+2]
    float s11 = w[3] + w[4] + w[5] + w[6] + w[7] + w[8]
              + w[9] + w[10] + w[11] + w[12] + w[13];              // x[o-5..o+5]
    #pragma unroll
    for (int k = 0; k < 8; ++k) {
        float r = fmaf(-0.2f, s5, w[8 + k]);
        r = (fabsf(r) > t1) ? r * C_SPIKE_D : r;
        pv[k] = fmaf(C_DETAIL, r, fmaf(B11, s11, B5 * s5));
        if (k < 7) { s5 += w[11 + k] - w[6 + k]; s11 += w[14 + k] - w[3 + k]; }
    }
}

// ---- K1: pass-1 residual partials (register-only; R13 form) ----
__global__ __launch_bounds__(NTHREADS) void k1_reduce(
    const float* __restrict__ x, double* __restrict__ partials1, int L) {
    int row = blockIdx.x / BPR, cgid = blockIdx.x % BPR;
    const float* rp = x + (size_t)row * L;
    double s = 0.0, s2 = 0.0;
    for (int i = 0; i < CPB; ++i) {
        int o = (cgid * CPB + i) * CHUNK + threadIdx.x * EPT;
        float w[16];
        if (o >= 4 && o + 12 <= L) {
            const float4* p = reinterpret_cast<const float4*>(rp + o - 4);
            #pragma unroll
            for (int j = 0; j < 4; ++j) {
                float4 v = p[j];
                w[4*j+0] = v.x; w[4*j+1] = v.y; w[4*j+2] = v.z; w[4*j+3] = v.w;
            }
        } else {
            #pragma unroll
            for (int j = 0; j < 16; ++j) w[j] = reflect_load(rp, o - 4 + j, L);
        }
        float s5 = w[2] + w[3] + w[4] + w[5] + w[6];
        #pragma unroll
        for (int k = 0; k < EPT; ++k) {
            float r = fmaf(-0.2f, s5, w[4 + k]);
            s += (double)r;
            s2 = fma((double)r, (double)r, s2);
            if (k < EPT - 1) s5 += w[7 + k] - w[2 + k];
        }
    }
    blk_reduce2(s, s2);
    if (threadIdx.x == 0) { partials1[2*blockIdx.x] = s; partials1[2*blockIdx.x+1] = s2; }
}

// ---- K2: direct-global x window; xp1 own-8 -> ping-pong LDS (halo +-2); pass-2 partials ----
__global__ __launch_bounds__(NTHREADS) void k2_reduce(
    const float* __restrict__ x, const double* __restrict__ partials1,
    double* __restrict__ partials2, int L) {
    __shared__ float xpbuf[2][SKEW(CHUNK + 4 - 1) + 1];   // m2 in [0, CHUNK+3]
    int row = blockIdx.x / BPR, cgid = blockIdx.x % BPR;
    const float* rp = x + (size_t)row * L;
    float t1 = thr128(partials1 + (size_t)row * 2 * BPR, L);
    int tid = threadIdx.x;
    double s = 0.0, s2 = 0.0;
    for (int i = 0; i < CPB; ++i) {
        float* xp = xpbuf[i & 1];
        int cb = (cgid * CPB + i) * CHUNK;
        int o = cb + tid * EPT;
        float w[24];
        load_w24(rp, o, L, w);
        float pv[8];
        xp1_slide8(w, t1, pv);
        int m2b = tid * EPT + 2;
        #pragma unroll
        for (int k = 0; k < 8; ++k) xp[SKEW(m2b + k)] = pv[k];
        if (tid < 2)                     xp[SKEW(tid)] = xp1_scalar(rp, L, cb - 2 + tid, t1);
        else if (tid >= 64 && tid < 66)  xp[SKEW(CHUNK + 2 + (tid-64))] = xp1_scalar(rp, L, cb + CHUNK + (tid-64), t1);
        __syncthreads();
        float v2[12];   // xp1 at [o-2 .. o+9]
        v2[0] = xp[SKEW(m2b - 2)];
        v2[1] = xp[SKEW(m2b - 1)];
        #pragma unroll
        for (int k = 0; k < 8; ++k) v2[2+k] = pv[k];
        v2[10] = xp[SKEW(m2b + 8)];
        v2[11] = xp[SKEW(m2b + 9)];
        float t5 = v2[0]+v2[1]+v2[2]+v2[3]+v2[4];
        #pragma unroll
        for (int k = 0; k < EPT; ++k) {
            float r2 = fmaf(-0.2f, t5, v2[2+k]);
            s += (double)r2;
            s2 = fma((double)r2, (double)r2, s2);
            if (k < EPT - 1) t5 += v2[5+k] - v2[k];
        }
        // no trailing barrier: next chunk writes the other buffer
    }
    blk_reduce2(s, s2);
    if (threadIdx.x == 0) { partials2[2*blockIdx.x] = s; partials2[2*blockIdx.x+1] = s2; }
}

// ---- K3: direct-global x window; xp1 own-8 -> ping-pong LDS (halo +-5); apply; write out ----
__global__ __launch_bounds__(NTHREADS) void k3_apply(
    const float* __restrict__ x, const double* __restrict__ partials1,
    const double* __restrict__ partials2, float* __restrict__ out, int L) {
    __shared__ float xpbuf[2][SKEW(CHUNK + 10 - 1) + 1];  // m2 in [0, CHUNK+9]
    int row = blockIdx.x / BPR, cgid = blockIdx.x % BPR;
    const float* rp = x + (size_t)row * L;
    float* orow = out + (size_t)row * L;
    float t1 = thr128(partials1 + (size_t)row * 2 * BPR, L);
    float t2 = thr128(partials2 + (size_t)row * 2 * BPR, L);
    int tid = threadIdx.x;
    for (int i = 0; i < CPB; ++i) {
        float* xp = xpbuf[i & 1];
        int cb = (cgid * CPB + i) * CHUNK;
        int o = cb + tid * EPT;
        float w[24];
        load_w24(rp, o, L, w);
        float pv[8];
        xp1_slide8(w, t1, pv);
        int m2b = tid * EPT + 5;
        #pragma unroll
        for (int k = 0; k < 8; ++k) xp[SKEW(m2b + k)] = pv[k];
        if (tid < 5)                     xp[SKEW(tid)] = xp1_scalar(rp, L, cb - 5 + tid, t1);
        else if (tid >= 64 && tid < 69)  xp[SKEW(CHUNK + 5 + (tid-64))] = xp1_scalar(rp, L, cb + CHUNK + (tid-64), t1);
        __syncthreads();
        float w2[18];   // xp1 at [o-5 .. o+12]
        #pragma unroll
        for (int j = 0; j < 5; ++j) w2[j]    = xp[SKEW(m2b - 5 + j)];
        #pragma unroll
        for (int k = 0; k < 8; ++k) w2[5+k]  = pv[k];
        #pragma unroll
        for (int j = 0; j < 5; ++j) w2[13+j] = xp[SKEW(m2b + 8 + j)];
        float res[EPT];
        {
            float s5  = w2[3]+w2[4]+w2[5]+w2[6]+w2[7];
            float s11 = w2[0]+w2[1]+w2[2]+w2[3]+w2[4]+w2[5]
                      + w2[6]+w2[7]+w2[8]+w2[9]+w2[10];
            #pragma unroll
            for (int k = 0; k < EPT; ++k) {
                float r = fmaf(-0.2f, s5, w2[5+k]);
                r = (fabsf(r) > t2) ? r * C_SPIKE_D : r;
                res[k] = fmaf(C_DETAIL, r, fmaf(B11, s11, B5 * s5));
                if (k < EPT - 1) { s5 += w2[8+k] - w2[3+k]; s11 += w2[11+k] - w2[k]; }
            }
        }
        vfloat4 r0 = { res[0], res[1], res[2], res[3] };
        vfloat4 r1 = { res[4], res[5], res[6], res[7] };
        __builtin_nontemporal_store(r0, reinterpret_cast<vfloat4*>(orow + o));
        __builtin_nontemporal_store(r1, reinterpret_cast<vfloat4*>(orow + o) + 1);
        // no trailing barrier: next chunk writes the other buffer
    }
}

extern "C" void kernel_launch(void* const* d_in, const int* in_sizes, int n_in,
                              void* d_out, int out_size, void* d_ws, size_t ws_size,
                              hipStream_t stream) {
    const float* x = (const float*)d_in[0];
    float* outp = (float*)d_out;

    int total = in_sizes[0];
    int L = total / ROWS;          // 1048576

    // workspace: [partials1 32KB][partials2 32KB]
    double* partials1 = (double*)d_ws;
    double* partials2 = partials1 + 2 * NB;

    k1_reduce<<<NB, NTHREADS, 0, stream>>>(x, partials1, L);
    k2_reduce<<<NB, NTHREADS, 0, stream>>>(x, partials1, partials2, L);
    k3_apply <<<NB, NTHREADS, 0, stream>>>(x, partials1, partials2, outp, L);
}